// Round 1
// baseline (173.992 us; speedup 1.0000x reference)
//
#include <hip/hip_runtime.h>

// TopKRouter: x[B=16,C=768,H=64,W=64] fp32, W[E=16,C=768], b[E=16], k=2.
// logits = einsum(bchw,ec->behw) + b ; scores = softmax_E ; top-2 renormalized.
// Outputs concatenated fp32: topk_probs[16,2,64,64] | topk_indices[16,2,64,64]
// (as float) | scores[16,16,64,64].

#define C_DIM 768
#define E_DIM 16
#define HW    4096   // 64*64
#define NPIX  65536  // 16*4096

__global__ __launch_bounds__(256) void topk_router_kernel(
    const float* __restrict__ x,     // [B, C, HW]
    const float* __restrict__ Wm,    // [E, C]
    const float* __restrict__ bias,  // [E]
    float* __restrict__ out)         // concat outputs
{
    const int g = blockIdx.x * 256 + threadIdx.x;  // global pixel id
    const int b = g >> 12;                         // / 4096 (block-uniform)
    const int p = g & 4095;

    const float* xp = x + (size_t)b * C_DIM * HW + p;

    float acc[E_DIM];
#pragma unroll
    for (int e = 0; e < E_DIM; ++e) acc[e] = 0.0f;

    // Inner product over channels. x access coalesced across lanes (stride-1
    // in p); W access is wave-uniform -> scalar loads. Unroll 16 to keep >=16
    // vector loads in flight (only 1 wave/SIMD at this grid size).
#pragma unroll 16
    for (int c = 0; c < C_DIM; ++c) {
        const float xv = xp[(size_t)c * HW];
#pragma unroll
        for (int e = 0; e < E_DIM; ++e)
            acc[e] = fmaf(xv, Wm[e * C_DIM + c], acc[e]);
    }

    // bias + softmax over experts (all in registers, 16 values per thread)
    float m = -INFINITY;
#pragma unroll
    for (int e = 0; e < E_DIM; ++e) {
        acc[e] += bias[e];
        m = fmaxf(m, acc[e]);
    }
    float pr[E_DIM];
    float sum = 0.0f;
#pragma unroll
    for (int e = 0; e < E_DIM; ++e) {
        pr[e] = __expf(acc[e] - m);
        sum += pr[e];
    }
    const float inv = 1.0f / sum;

    // scores output: offset 2*131072 floats
    float* scores = out + 262144;
#pragma unroll
    for (int e = 0; e < E_DIM; ++e) {
        const float s = pr[e] * inv;
        pr[e] = s;
        scores[((size_t)b * E_DIM + e) * HW + p] = s;
    }

    // top-2 (ties -> lower index, matching jax.lax.top_k)
    int i1 = 0;
    float p1 = pr[0];
#pragma unroll
    for (int e = 1; e < E_DIM; ++e)
        if (pr[e] > p1) { p1 = pr[e]; i1 = e; }
    int i2 = -1;
    float p2 = -INFINITY;
#pragma unroll
    for (int e = 0; e < E_DIM; ++e)
        if (e != i1 && pr[e] > p2) { p2 = pr[e]; i2 = e; }

    const float rs = 1.0f / (p1 + p2);
    const size_t o1 = ((size_t)b * 2 + 0) * HW + p;
    const size_t o2 = ((size_t)b * 2 + 1) * HW + p;
    out[o1] = p1 * rs;              // topk_probs
    out[o2] = p2 * rs;
    float* idxo = out + 131072;     // topk_indices (as float)
    idxo[o1] = (float)i1;
    idxo[o2] = (float)i2;
}

extern "C" void kernel_launch(void* const* d_in, const int* in_sizes, int n_in,
                              void* d_out, int out_size, void* d_ws, size_t ws_size,
                              hipStream_t stream) {
    const float* x  = (const float*)d_in[0];
    const float* Wm = (const float*)d_in[1];
    const float* bs = (const float*)d_in[2];
    // d_in[3] = active_experts (always 2 per setup_inputs)
    float* out = (float*)d_out;

    topk_router_kernel<<<NPIX / 256, 256, 0, stream>>>(x, Wm, bs, out);
}

// Round 2
// 71.238 us; speedup vs baseline: 2.4424x; 2.4424x over previous
//
#include <hip/hip_runtime.h>

// TopKRouter: x[B=16,C=768,H=64,W=64] fp32, W[E=16,C=768], b[E=16], k=2.
// Two-phase: (1) C-split partial logits -> ws, (2) reduce+softmax+top2.
// Outputs concatenated fp32: topk_probs[16,2,64,64] | topk_indices[16,2,64,64]
// (as float) | scores[16,16,64,64].

#define C_DIM 768
#define E_DIM 16
#define HW    4096   // 64*64
#define NPIX  65536  // 16*4096

// ---------------- Phase 1: partial logits over a channel segment ----------
// Each thread: 4 consecutive pixels (float4 loads, 16B/lane).
// blockIdx.x -> pixel group (64 blocks x 256 thr x 4 pix = 65536)
// blockIdx.y -> channel segment (CL channels each)
template <int CL>
__global__ __launch_bounds__(256) void router_partial(
    const float* __restrict__ x,   // [B, C, HW]
    const float* __restrict__ Wm,  // [E, C]
    float* __restrict__ ws)        // [CS, E, NPIX] partial logits
{
    const int seg = blockIdx.y;
    const int c0  = seg * CL;
    const int pg  = (blockIdx.x * 256 + threadIdx.x) * 4;  // first pixel
    const int b   = pg >> 12;
    const int p   = pg & 4095;
    const float* xp = x + (size_t)b * C_DIM * HW + p;

    float4 acc[E_DIM];
#pragma unroll
    for (int e = 0; e < E_DIM; ++e) acc[e] = make_float4(0.f, 0.f, 0.f, 0.f);

#pragma unroll 8
    for (int c = c0; c < c0 + CL; ++c) {
        const float4 xv = *reinterpret_cast<const float4*>(xp + (size_t)c * HW);
#pragma unroll
        for (int e = 0; e < E_DIM; ++e) {
            const float w = Wm[e * C_DIM + c];  // wave-uniform -> SGPR
            acc[e].x = fmaf(xv.x, w, acc[e].x);
            acc[e].y = fmaf(xv.y, w, acc[e].y);
            acc[e].z = fmaf(xv.z, w, acc[e].z);
            acc[e].w = fmaf(xv.w, w, acc[e].w);
        }
    }

#pragma unroll
    for (int e = 0; e < E_DIM; ++e)
        *reinterpret_cast<float4*>(ws + (size_t)(seg * E_DIM + e) * NPIX + pg) = acc[e];
}

// ---------------- Phase 2: reduce segments + bias + softmax + top2 --------
template <int CS>
__global__ __launch_bounds__(256) void router_finish(
    const float* __restrict__ ws,    // [CS, E, NPIX]
    const float* __restrict__ bias,  // [E]
    float* __restrict__ out)
{
    const int g = blockIdx.x * 256 + threadIdx.x;  // pixel id
    const int b = g >> 12;
    const int p = g & 4095;

    float lg[E_DIM];
#pragma unroll
    for (int e = 0; e < E_DIM; ++e) lg[e] = bias[e];
#pragma unroll
    for (int s = 0; s < CS; ++s)
#pragma unroll
        for (int e = 0; e < E_DIM; ++e)
            lg[e] += ws[(size_t)(s * E_DIM + e) * NPIX + g];

    float m = -INFINITY;
#pragma unroll
    for (int e = 0; e < E_DIM; ++e) m = fmaxf(m, lg[e]);
    float pr[E_DIM];
    float sum = 0.0f;
#pragma unroll
    for (int e = 0; e < E_DIM; ++e) {
        pr[e] = __expf(lg[e] - m);
        sum += pr[e];
    }
    const float inv = 1.0f / sum;

    float* scores = out + 262144;
#pragma unroll
    for (int e = 0; e < E_DIM; ++e) {
        const float s = pr[e] * inv;
        pr[e] = s;
        scores[(size_t)(b * E_DIM + e) * HW + p] = s;
    }

    // top-2, ties -> lower index (matches jax.lax.top_k)
    int i1 = 0;
    float p1 = pr[0];
#pragma unroll
    for (int e = 1; e < E_DIM; ++e)
        if (pr[e] > p1) { p1 = pr[e]; i1 = e; }
    int i2 = -1;
    float p2 = -INFINITY;
#pragma unroll
    for (int e = 0; e < E_DIM; ++e)
        if (e != i1 && pr[e] > p2) { p2 = pr[e]; i2 = e; }

    const float rs = 1.0f / (p1 + p2);
    const size_t o1 = (size_t)(b * 2 + 0) * HW + p;
    const size_t o2 = (size_t)(b * 2 + 1) * HW + p;
    out[o1] = p1 * rs;
    out[o2] = p2 * rs;
    float* idxo = out + 131072;
    idxo[o1] = (float)i1;
    idxo[o2] = (float)i2;
}

// ---------------- Fallback: fused single-pass (if ws too small) -----------
__global__ __launch_bounds__(256) void topk_router_fused(
    const float* __restrict__ x, const float* __restrict__ Wm,
    const float* __restrict__ bias, float* __restrict__ out)
{
    const int g = blockIdx.x * 256 + threadIdx.x;
    const int b = g >> 12;
    const int p = g & 4095;
    const float* xp = x + (size_t)b * C_DIM * HW + p;

    float acc[E_DIM];
#pragma unroll
    for (int e = 0; e < E_DIM; ++e) acc[e] = 0.0f;
#pragma unroll 16
    for (int c = 0; c < C_DIM; ++c) {
        const float xv = xp[(size_t)c * HW];
#pragma unroll
        for (int e = 0; e < E_DIM; ++e)
            acc[e] = fmaf(xv, Wm[e * C_DIM + c], acc[e]);
    }
    float m = -INFINITY;
#pragma unroll
    for (int e = 0; e < E_DIM; ++e) { acc[e] += bias[e]; m = fmaxf(m, acc[e]); }
    float pr[E_DIM]; float sum = 0.0f;
#pragma unroll
    for (int e = 0; e < E_DIM; ++e) { pr[e] = __expf(acc[e] - m); sum += pr[e]; }
    const float inv = 1.0f / sum;
    float* scores = out + 262144;
#pragma unroll
    for (int e = 0; e < E_DIM; ++e) {
        const float s = pr[e] * inv; pr[e] = s;
        scores[(size_t)(b * E_DIM + e) * HW + p] = s;
    }
    int i1 = 0; float p1 = pr[0];
#pragma unroll
    for (int e = 1; e < E_DIM; ++e) if (pr[e] > p1) { p1 = pr[e]; i1 = e; }
    int i2 = -1; float p2 = -INFINITY;
#pragma unroll
    for (int e = 0; e < E_DIM; ++e) if (e != i1 && pr[e] > p2) { p2 = pr[e]; i2 = e; }
    const float rs = 1.0f / (p1 + p2);
    const size_t o1 = (size_t)(b * 2 + 0) * HW + p;
    const size_t o2 = (size_t)(b * 2 + 1) * HW + p;
    out[o1] = p1 * rs; out[o2] = p2 * rs;
    float* idxo = out + 131072;
    idxo[o1] = (float)i1; idxo[o2] = (float)i2;
}

extern "C" void kernel_launch(void* const* d_in, const int* in_sizes, int n_in,
                              void* d_out, int out_size, void* d_ws, size_t ws_size,
                              hipStream_t stream) {
    const float* x  = (const float*)d_in[0];
    const float* Wm = (const float*)d_in[1];
    const float* bs = (const float*)d_in[2];
    float* out = (float*)d_out;
    float* ws  = (float*)d_ws;

    const size_t seg_bytes = (size_t)E_DIM * NPIX * sizeof(float);  // 4 MB

    if (ws_size >= 8 * seg_bytes) {
        router_partial<96><<<dim3(64, 8), 256, 0, stream>>>(x, Wm, ws);
        router_finish<8><<<NPIX / 256, 256, 0, stream>>>(ws, bs, out);
    } else if (ws_size >= 4 * seg_bytes) {
        router_partial<192><<<dim3(64, 4), 256, 0, stream>>>(x, Wm, ws);
        router_finish<4><<<NPIX / 256, 256, 0, stream>>>(ws, bs, out);
    } else if (ws_size >= 2 * seg_bytes) {
        router_partial<384><<<dim3(64, 2), 256, 0, stream>>>(x, Wm, ws);
        router_finish<2><<<NPIX / 256, 256, 0, stream>>>(ws, bs, out);
    } else if (ws_size >= seg_bytes) {
        router_partial<768><<<dim3(64, 1), 256, 0, stream>>>(x, Wm, ws);
        router_finish<1><<<NPIX / 256, 256, 0, stream>>>(ws, bs, out);
    } else {
        topk_router_fused<<<NPIX / 256, 256, 0, stream>>>(x, Wm, bs, out);
    }
}